// Round 16
// baseline (389.282 us; speedup 1.0000x reference)
//
#include <hip/hip_runtime.h>
#include <hip/hip_bf16.h>
#include <cstddef>

// BS=8, NE=128, ENT=768, REL=768, RANK=256, OUT=256
// M = 131072 rows; rel row-major [b][i][j][768]
// ws: l1 [1024*256 f32] | l2 [1024*256 f32] | W3g [196608 bf16 frag] | Weg [65536 bf16 frag]
// Fragment-major B panels: flat = ((kq*256 + n)*4 + g)*8 + e (kq=k/32, g=(k/8)%4, e=k%8)
//
// R16 — M-SPLIT, FULLY BARRIER-FREE:
//   Wave owns rows wave*16..+15, all 256 N-cols (acc1[16] f32x4 = 64 regs).
//   A(rel): direct global->reg (8 consecutive f32/lane, 16x128B lines, zero
//   redundancy), cvt in-reg; 2-generation prefetch issued AFTER B each iter
//   (FIFO law: B-waits drain older A; keep A ~1-2 iters old, stagger waves).
//   B(W3g/Weg): fragment-major 1KB loads, chunked 4-at-a-time, compiler-
//   pipelined. prod: wave-private LDS tile [16][256] (GEMM2 transpose only).
//   LN: wave-local (in-lane fn + shfl_xor over c16). ZERO barriers anywhere.
//   B-role/output mapping mirrors R14's gemm2_ln kernel (verified on-device).

typedef __attribute__((ext_vector_type(8))) short short8;
typedef __attribute__((ext_vector_type(4))) float f32x4;

__device__ __forceinline__ unsigned short f2bf(float x) {
  union { float f; unsigned u; } v; v.f = x;
  unsigned r = (v.u + 0x7FFFu + ((v.u >> 16) & 1u)) >> 16;  // RNE
  return (unsigned short)r;
}
__device__ __forceinline__ unsigned short cvt1(float x) {
  return __bfloat16_as_ushort(__float2bfloat16(x));  // pairs to v_cvt_pk_bf16_f32
}
__device__ __forceinline__ f32x4 mfma16(short8 a, short8 b, f32x4 c) {
  return __builtin_amdgcn_mfma_f32_16x16x32_bf16(a, b, c, 0, 0, 0);
}
__device__ __forceinline__ short8 pk8(f32x4 x, f32x4 y) {
  short8 s;
  s[0] = (short)cvt1(x[0]); s[1] = (short)cvt1(x[1]);
  s[2] = (short)cvt1(x[2]); s[3] = (short)cvt1(x[3]);
  s[4] = (short)cvt1(y[0]); s[5] = (short)cvt1(y[1]);
  s[6] = (short)cvt1(y[2]); s[7] = (short)cvt1(y[3]);
  return s;
}

// ---------------- prep (grid 1280) -------------------------------------------
__global__ __launch_bounds__(256) void prep_all(
    const float* __restrict__ sub, const float* __restrict__ obj,
    const float* __restrict__ W1, const float* __restrict__ b1,
    const float* __restrict__ W2, const float* __restrict__ b2,
    const float* __restrict__ W3, const float* __restrict__ We,
    float* __restrict__ l1p, float* __restrict__ l2p,
    unsigned short* __restrict__ W3g, unsigned short* __restrict__ Weg) {
  const int tid = threadIdx.x;
  if (blockIdx.x >= 256) {
    int idx = (blockIdx.x - 256) * 256 + tid;
    if (idx < 196608) {
      int n = idx / 768, k = idx % 768;
      int f = ((k >> 5) * 256 + n) * 32 + ((k >> 3) & 3) * 8 + (k & 7);
      W3g[f] = f2bf(W3[idx]);
    }
    int j = idx - 196608;
    if (j >= 0 && j < 65536) {
      int n = j / 256, k = j % 256;
      int f = ((k >> 5) * 256 + n) * 32 + ((k >> 3) & 3) * 8 + (k & 7);
      Weg[f] = f2bf(We[j]);
    }
    return;
  }
  const int half = blockIdx.x >> 7;
  const float* x = half ? obj : sub;
  const float* W = half ? W2 : W1;
  const float* bias = half ? b2 : b1;
  float* outp = half ? l2p : l1p;

  __shared__ float xs[8][768];
  const int R0 = (blockIdx.x & 127) * 8;
  #pragma unroll
  for (int c = 0; c < 6; ++c) {
    int f4i = c * 256 + tid;
    int row = f4i / 192;
    int c4 = f4i % 192;
    *(float4*)&xs[row][c4 * 4] = *(const float4*)&x[(size_t)(R0 + row) * 768 + c4 * 4];
  }
  __syncthreads();
  const int col = tid;
  const float* Wr = W + (size_t)col * 768;
  float a[8] = {0.f, 0.f, 0.f, 0.f, 0.f, 0.f, 0.f, 0.f};
  for (int k4 = 0; k4 < 192; ++k4) {
    float4 wv = *(const float4*)&Wr[k4 * 4];
    #pragma unroll
    for (int r = 0; r < 8; ++r) {
      float4 xv = *(const float4*)&xs[r][k4 * 4];
      a[r] += wv.x * xv.x + wv.y * xv.y + wv.z * xv.z + wv.w * xv.w;
    }
  }
  float bb = bias[col];
  #pragma unroll
  for (int r = 0; r < 8; ++r)
    outp[(size_t)(R0 + r) * 256 + col] = a[r] + bb;
}

// ---------------- fused main (barrier-free) -----------------------------------
__global__ __launch_bounds__(256, 3) void fused_main(
    const float* __restrict__ rel, const float* __restrict__ l1p,
    const float* __restrict__ l2p, const unsigned short* __restrict__ W3g,
    const unsigned short* __restrict__ Weg, const float* __restrict__ b3,
    const float* __restrict__ be, const float* __restrict__ lng,
    const float* __restrict__ lnb, float* __restrict__ out) {
  __shared__ unsigned short prodS[4][16][256];  // wave-private 8KB tiles; 32 KB

  const int tid = threadIdx.x;
  const int wave = tid >> 6, lane = tid & 63;
  const int g = lane >> 4, c16 = lane & 15;

  // XCD-bijective swizzle (2048 % 8 == 0)
  const int bid = (blockIdx.x & 7) * 256 + (blockIdx.x >> 3);
  const int R0 = bid * 64;
  const int b = R0 >> 14;
  const int rem = R0 & 16383;
  const int i = rem >> 7;
  const int j0 = rem & 127;  // 0 or 64

  // wave's 16 rows: global rows R0 + wave*16 .. +15
  const float* aptr =
      rel + (size_t)((b * 128 + i) * 128 + j0 + wave * 16 + c16) * 768 + g * 8;
  const unsigned short* bp3 = W3g + (size_t)c16 * 32 + g * 8;
  const unsigned short* bp2 = Weg + (size_t)c16 * 32 + g * 8;

  f32x4 acc1[16] = {};      // [fn], col = fn*16 + c16
  f32x4 avA[2][2][2];       // [gen][sub][half] — static-indexed (full unroll)

#define LOADA(G, KS)                                                           \
  {                                                                            \
    const float* p0_ = aptr + (size_t)(KS) * 64;                               \
    avA[G][0][0] = *(const f32x4*)(p0_);                                       \
    avA[G][0][1] = *(const f32x4*)(p0_ + 4);                                   \
    avA[G][1][0] = *(const f32x4*)(p0_ + 32);                                  \
    avA[G][1][1] = *(const f32x4*)(p0_ + 36);                                  \
  }

  // prologue: generations 0 and 1 in flight
  LOADA(0, 0);
  LOADA(1, 1);

  #pragma unroll
  for (int ks = 0; ks < 12; ++ks) {
    const int cur = ks & 1;
    // cvt A(ks) -> bf16 frags (compiler waits counted vmcnt; A is ~2 iters old)
    short8 ah0 = pk8(avA[cur][0][0], avA[cur][0][1]);
    short8 ah1 = pk8(avA[cur][1][0], avA[cur][1][1]);
    // B chunks (L2-fast) + MFMA; compiler pipelines chunk c+1 loads over chunk c
    #pragma unroll
    for (int sub = 0; sub < 2; ++sub) {
      const short8 ah = sub ? ah1 : ah0;
      const unsigned short* bk = bp3 + (size_t)(ks * 2 + sub) * 8192;
      #pragma unroll
      for (int fc = 0; fc < 4; ++fc) {
        short8 b0 = *(const short8*)(bk + (fc * 4 + 0) * 512);
        short8 b1 = *(const short8*)(bk + (fc * 4 + 1) * 512);
        short8 b2v = *(const short8*)(bk + (fc * 4 + 2) * 512);
        short8 b3v = *(const short8*)(bk + (fc * 4 + 3) * 512);
        acc1[fc * 4 + 0] = mfma16(ah, b0, acc1[fc * 4 + 0]);
        acc1[fc * 4 + 1] = mfma16(ah, b1, acc1[fc * 4 + 1]);
        acc1[fc * 4 + 2] = mfma16(ah, b2v, acc1[fc * 4 + 2]);
        acc1[fc * 4 + 3] = mfma16(ah, b3v, acc1[fc * 4 + 3]);
      }
    }
    // A(ks+2) issued AFTER this iter's B loads (FIFO discipline)
    __builtin_amdgcn_sched_barrier(0);
    if (ks < 10) LOADA(cur, ks + 2);
    __builtin_amdgcn_sched_barrier(0);
  }

  // ---- epilogue 1: prod = (l3 + b3) * l1 * l2 -> wave-private bf16 LDS ----
  const float* l1row = l1p + (size_t)(b * 128 + i) * 256;
  float l1v[16], b3v[16];
  #pragma unroll
  for (int fn = 0; fn < 16; ++fn) {
    l1v[fn] = l1row[fn * 16 + c16];
    b3v[fn] = b3[fn * 16 + c16];
  }
  #pragma unroll
  for (int r = 0; r < 4; ++r) {
    const int lr = g * 4 + r;  // local row 0..15
    const float* l2row = l2p + (size_t)(b * 128 + j0 + wave * 16 + lr) * 256;
    const int sw = (lr & 7) << 3;
    #pragma unroll
    for (int fn = 0; fn < 16; ++fn) {
      float v = (acc1[fn][r] + b3v[fn]) * l1v[fn] * l2row[fn * 16 + c16];
      prodS[wave][lr][(fn * 16 + c16) ^ sw] = f2bf(v);
    }
  }
  // no barrier: same-wave ds_write -> ds_read ordered via lgkmcnt (compiler)

  // ---- GEMM2: f = prod @ Web^T (wave-private LDS A, Weg frag-major B) ----
  f32x4 acc2[16] = {};
  const int sw2 = (c16 & 7) << 3;
  #pragma unroll
  for (int kk = 0; kk < 8; ++kk) {
    short8 a2 = *(const short8*)&prodS[wave][c16][(kk * 32 + g * 8) ^ sw2];
    const unsigned short* bk = bp2 + (size_t)kk * 8192;
    #pragma unroll
    for (int fc = 0; fc < 4; ++fc) {
      short8 b0 = *(const short8*)(bk + (fc * 4 + 0) * 512);
      short8 b1 = *(const short8*)(bk + (fc * 4 + 1) * 512);
      short8 b2v = *(const short8*)(bk + (fc * 4 + 2) * 512);
      short8 b3q = *(const short8*)(bk + (fc * 4 + 3) * 512);
      acc2[fc * 4 + 0] = mfma16(a2, b0, acc2[fc * 4 + 0]);
      acc2[fc * 4 + 1] = mfma16(a2, b1, acc2[fc * 4 + 1]);
      acc2[fc * 4 + 2] = mfma16(a2, b2v, acc2[fc * 4 + 2]);
      acc2[fc * 4 + 3] = mfma16(a2, b3q, acc2[fc * 4 + 3]);
    }
  }

  // ---- LN (wave-local) + store ----
  float bev[16], gv[16], bhv[16];
  #pragma unroll
  for (int fn = 0; fn < 16; ++fn) {
    bev[fn] = be[fn * 16 + c16];
    gv[fn] = lng[fn * 16 + c16];
    bhv[fn] = lnb[fn * 16 + c16];
  }
  #pragma unroll
  for (int r = 0; r < 4; ++r) {
    float s1 = 0.f, s2 = 0.f;
    #pragma unroll
    for (int fn = 0; fn < 16; ++fn) {
      float v = acc2[fn][r] + bev[fn];
      s1 += v; s2 += v * v;
    }
    #pragma unroll
    for (int off = 1; off < 16; off <<= 1) {
      s1 += __shfl_xor(s1, off);
      s2 += __shfl_xor(s2, off);
    }
    const float mu = s1 * 0.00390625f;
    const float rs = rsqrtf(s2 * 0.00390625f - mu * mu + 1e-6f);
    float* orow = out + (size_t)(R0 + wave * 16 + g * 4 + r) * 256;
    #pragma unroll
    for (int fn = 0; fn < 16; ++fn) {
      float v = acc2[fn][r] + bev[fn];
      orow[fn * 16 + c16] = (v - mu) * rs * gv[fn] + bhv[fn];
    }
  }
#undef LOADA
}

extern "C" void kernel_launch(void* const* d_in, const int* in_sizes, int n_in,
                              void* d_out, int out_size, void* d_ws, size_t ws_size,
                              hipStream_t stream) {
  const float* sub = (const float*)d_in[0];
  const float* obj = (const float*)d_in[1];
  const float* rel = (const float*)d_in[2];
  const float* W1 = (const float*)d_in[3];
  const float* b1 = (const float*)d_in[4];
  const float* W2 = (const float*)d_in[5];
  const float* b2 = (const float*)d_in[6];
  const float* W3 = (const float*)d_in[7];
  const float* b3 = (const float*)d_in[8];
  const float* We = (const float*)d_in[9];
  const float* be = (const float*)d_in[10];
  const float* lng = (const float*)d_in[11];
  const float* lnb = (const float*)d_in[12];
  float* out = (float*)d_out;

  float* ws = (float*)d_ws;
  float* l1p = ws;
  float* l2p = ws + 262144;
  unsigned short* W3g = (unsigned short*)(ws + 524288);
  unsigned short* Weg = W3g + 196608;

  prep_all<<<1280, 256, 0, stream>>>(sub, obj, W1, b1, W2, b2, W3, We, l1p, l2p, W3g, Weg);
  fused_main<<<2048, 256, 0, stream>>>(rel, l1p, l2p, W3g, Weg, b3, be, lng, lnb, out);
}

// Round 17
// 209.249 us; speedup vs baseline: 1.8604x; 1.8604x over previous
//
#include <hip/hip_runtime.h>
#include <hip/hip_bf16.h>
#include <cstddef>

// BS=8, NE=128, ENT=768, REL=768, RANK=256, OUT=256
// M = 131072 rows; rel row-major [b][i][j][768]
// ws: l1 [1024*256 f32] | l2 [1024*256 f32] | W3g [196608 bf16 frag] | Weg [65536 bf16 frag]
// Fragment-major B panels: flat = ((kq*256 + n)*4 + g)*8 + e (kq=k/32, g=(k/8)%4, e=k%8)
//
// R17 — M=128 TILE (512 thr, 8 waves = 2 row-groups x 4 col-groups):
//   Binder hypothesis from R9-family data: K-loop pinned at ~1575 cy/iter ~= 
//   per-CU L2 feed ceiling for B panels (3 blocks x 32KB/iter ~ 61 B/cy vs ~56
//   ceiling). Geometry fix: 128-row block -> same 32KB B k-slice feeds 2x rows
//   (B traffic 786->393 MB); h=0/1 waves re-read identical lines back-to-back
//   (L1-served). Tile = full j-range (j0 gone). LDS: stg dbuf 32KB U prod 64KB
//   + LN 5KB ~= 69KB -> 2 blocks/CU = 16 waves (vs R9's 12).
//   Schedule: verified R15 diet (B_ 8 upfront, 1-gen A prefetch, raw lgkm-only
//   barrier, counted vmcnt by compiler, XCD-bijective swizzle). VGPR target
//   <=128 via launch_bounds(512,4); go/no-go = VGPR_Count & Occupancy.

typedef __attribute__((ext_vector_type(8))) short short8;
typedef __attribute__((ext_vector_type(4))) float f32x4;

__device__ __forceinline__ unsigned short f2bf(float x) {
  union { float f; unsigned u; } v; v.f = x;
  unsigned r = (v.u + 0x7FFFu + ((v.u >> 16) & 1u)) >> 16;  // RNE
  return (unsigned short)r;
}
__device__ __forceinline__ unsigned short cvt1(float x) {
  return __bfloat16_as_ushort(__float2bfloat16(x));  // pairs to v_cvt_pk_bf16_f32
}
__device__ __forceinline__ f32x4 mfma16(short8 a, short8 b, f32x4 c) {
  return __builtin_amdgcn_mfma_f32_16x16x32_bf16(a, b, c, 0, 0, 0);
}
__device__ __forceinline__ short8 pk8(f32x4 x, f32x4 y) {
  short8 s;
  s[0] = (short)cvt1(x[0]); s[1] = (short)cvt1(x[1]);
  s[2] = (short)cvt1(x[2]); s[3] = (short)cvt1(x[3]);
  s[4] = (short)cvt1(y[0]); s[5] = (short)cvt1(y[1]);
  s[6] = (short)cvt1(y[2]); s[7] = (short)cvt1(y[3]);
  return s;
}

// ---------------- prep (grid 1280) -------------------------------------------
__global__ __launch_bounds__(256) void prep_all(
    const float* __restrict__ sub, const float* __restrict__ obj,
    const float* __restrict__ W1, const float* __restrict__ b1,
    const float* __restrict__ W2, const float* __restrict__ b2,
    const float* __restrict__ W3, const float* __restrict__ We,
    float* __restrict__ l1p, float* __restrict__ l2p,
    unsigned short* __restrict__ W3g, unsigned short* __restrict__ Weg) {
  const int tid = threadIdx.x;
  if (blockIdx.x >= 256) {
    int idx = (blockIdx.x - 256) * 256 + tid;
    if (idx < 196608) {
      int n = idx / 768, k = idx % 768;
      int f = ((k >> 5) * 256 + n) * 32 + ((k >> 3) & 3) * 8 + (k & 7);
      W3g[f] = f2bf(W3[idx]);
    }
    int j = idx - 196608;
    if (j >= 0 && j < 65536) {
      int n = j / 256, k = j % 256;
      int f = ((k >> 5) * 256 + n) * 32 + ((k >> 3) & 3) * 8 + (k & 7);
      Weg[f] = f2bf(We[j]);
    }
    return;
  }
  const int half = blockIdx.x >> 7;
  const float* x = half ? obj : sub;
  const float* W = half ? W2 : W1;
  const float* bias = half ? b2 : b1;
  float* outp = half ? l2p : l1p;

  __shared__ float xs[8][768];
  const int R0 = (blockIdx.x & 127) * 8;
  #pragma unroll
  for (int c = 0; c < 6; ++c) {
    int f4i = c * 256 + tid;
    int row = f4i / 192;
    int c4 = f4i % 192;
    *(float4*)&xs[row][c4 * 4] = *(const float4*)&x[(size_t)(R0 + row) * 768 + c4 * 4];
  }
  __syncthreads();
  const int col = tid;
  const float* Wr = W + (size_t)col * 768;
  float a[8] = {0.f, 0.f, 0.f, 0.f, 0.f, 0.f, 0.f, 0.f};
  for (int k4 = 0; k4 < 192; ++k4) {
    float4 wv = *(const float4*)&Wr[k4 * 4];
    #pragma unroll
    for (int r = 0; r < 8; ++r) {
      float4 xv = *(const float4*)&xs[r][k4 * 4];
      a[r] += wv.x * xv.x + wv.y * xv.y + wv.z * xv.z + wv.w * xv.w;
    }
  }
  float bb = bias[col];
  #pragma unroll
  for (int r = 0; r < 8; ++r)
    outp[(size_t)(R0 + r) * 256 + col] = a[r] + bb;
}

// ---------------- fused main (M=128, 512 threads) -----------------------------
__global__ __launch_bounds__(512, 4) void fused_main(
    const float* __restrict__ rel, const float* __restrict__ l1p,
    const float* __restrict__ l2p, const unsigned short* __restrict__ W3g,
    const unsigned short* __restrict__ Weg, const float* __restrict__ b3,
    const float* __restrict__ be, const float* __restrict__ lng,
    const float* __restrict__ lnb, float* __restrict__ out) {
  __shared__ union U {
    unsigned short stg[2][128][64];  // 32 KB bf16 staging (verified layout)
    unsigned short prod[128][256];   // 64 KB
  } u;
  __shared__ float ps[128][4], pq[128][4], mus[128], rss[128];  // 5 KB

  const int tid = threadIdx.x;
  const int wave = tid >> 6, lane = tid & 63;
  const int g = lane >> 4, c16 = lane & 15;
  const int h = wave >> 2;    // row-group 0/1 (64 rows each)
  const int cg = wave & 3;    // col-group (64 cols each)

  // XCD-bijective swizzle (1024 % 8 == 0)
  const int bid = (blockIdx.x & 7) * 128 + (blockIdx.x >> 3);
  const int R0 = bid * 128;           // block covers full j-range of one (b,i)
  const int b = R0 >> 14;
  const int i = (R0 & 16383) >> 7;

  const float* relBase = rel + (size_t)((b * 128 + i) * 128) * 768;

  // staging geometry (verified): wave stages rows wave*16 .. +15.
  const int sr4 = lane >> 2, c4 = lane & 3;
  const int rr = wave * 16 + sr4;
  const float* aG = relBase + (size_t)rr * 768 + c4 * 16;
  unsigned short* stW0 = &u.stg[0][rr][((c4 * 2) ^ (rr & 7)) * 8];
  unsigned short* stW1 = &u.stg[0][rr][((c4 * 2 + 1) ^ (rr & 7)) * 8];

  // B: fragment-major W3g; n = cg*64 + fn*16 + c16
  const unsigned short* bp = W3g + (size_t)(cg * 64 + c16) * 32 + g * 8;

  f32x4 acc1[4][4] = {};
  f32x4 av[4];   // single-generation A prefetch
  short8 B_[8];

#define SCHED0 __builtin_amdgcn_sched_barrier(0)
#define RAW_BARRIER                                           \
  do {                                                        \
    SCHED0;                                                   \
    asm volatile("s_waitcnt lgkmcnt(0)" ::: "memory");        \
    SCHED0;                                                   \
    __builtin_amdgcn_s_barrier();                             \
    SCHED0;                                                   \
  } while (0)

#define LOADA(KS)                                                              \
  {                                                                            \
    const float* p_ = aG + (size_t)(KS) * 64;                                  \
    av[0] = *(const f32x4*)(p_);                                               \
    av[1] = *(const f32x4*)(p_ + 4);                                           \
    av[2] = *(const f32x4*)(p_ + 8);                                           \
    av[3] = *(const f32x4*)(p_ + 12);                                          \
  }
#define WRITEA(BUF)                                                            \
  {                                                                            \
    *(short8*)(stW0 + (BUF) * 8192) = pk8(av[0], av[1]);                       \
    *(short8*)(stW1 + (BUF) * 8192) = pk8(av[2], av[3]);                       \
  }

  // prologue
  LOADA(0);
  WRITEA(0);
  RAW_BARRIER;

  #pragma unroll
  for (int ks = 0; ks < 12; ++ks) {
    const int buf = ks & 1;
    // B(ks) first (L2/L1-fast), A(ks+1) second (HBM-slow)
    #pragma unroll
    for (int sub = 0; sub < 2; ++sub)
      #pragma unroll
      for (int fn = 0; fn < 4; ++fn)
        B_[sub * 4 + fn] =
            *(const short8*)(bp + (size_t)(ks * 2 + sub) * 8192 + fn * 512);
    if (ks < 11) LOADA(ks + 1);
    SCHED0;
    __builtin_amdgcn_s_setprio(1);
    #pragma unroll
    for (int sub = 0; sub < 2; ++sub) {
      #pragma unroll
      for (int fm = 0; fm < 4; ++fm) {
        const int r = h * 64 + fm * 16 + c16;
        short8 ah = *(const short8*)&u.stg[buf][r][((sub * 4 + g) ^ (r & 7)) * 8];
        #pragma unroll
        for (int fn = 0; fn < 4; ++fn)
          acc1[fm][fn] = mfma16(ah, B_[sub * 4 + fn], acc1[fm][fn]);
      }
    }
    __builtin_amdgcn_s_setprio(0);
    SCHED0;
    if (ks < 11) {
      WRITEA(buf ^ 1);
      RAW_BARRIER;
    }
  }
  __syncthreads();  // queue empty; protects stg -> prod overlay

  // ---- epilogue 1: prod = (l3 + b3) * l1 * l2 -> bf16 swizzled LDS ----
  const int colb = cg * 64 + c16;
  const float* l1row = l1p + (size_t)(b * 128 + i) * 256;
  float l1v[4], b3v[4];
  #pragma unroll
  for (int fn = 0; fn < 4; ++fn) {
    l1v[fn] = l1row[colb + fn * 16];
    b3v[fn] = b3[colb + fn * 16];
  }
  #pragma unroll
  for (int fm = 0; fm < 4; ++fm) {
    #pragma unroll
    for (int r = 0; r < 4; ++r) {
      const int m = h * 64 + fm * 16 + g * 4 + r;  // local row = j
      const float* l2row = l2p + (size_t)(b * 128 + m) * 256;
      #pragma unroll
      for (int fn = 0; fn < 4; ++fn) {
        float v = (acc1[fm][fn][r] + b3v[fn]) * l1v[fn] * l2row[colb + fn * 16];
        u.prod[m][(colb + fn * 16) ^ ((m & 7) << 3)] = f2bf(v);
      }
    }
  }
  __syncthreads();

  // ---- GEMM2: f = prod @ Web^T (Weg fragment-major) ----
  f32x4 acc2[4][4] = {};
  #pragma unroll
  for (int kk = 0; kk < 8; ++kk) {
    short8 a2[4];
    #pragma unroll
    for (int fm = 0; fm < 4; ++fm) {
      const int m = h * 64 + fm * 16 + c16;
      a2[fm] = *(const short8*)&u.prod[m][(kk * 32 + g * 8) ^ ((m & 7) << 3)];
    }
    #pragma unroll
    for (int fn = 0; fn < 4; ++fn) {
      short8 bfr = *(const short8*)&Weg[(size_t)((kk * 256 + colb + fn * 16) * 4 + g) * 8];
      #pragma unroll
      for (int fm = 0; fm < 4; ++fm)
        acc2[fm][fn] = mfma16(a2[fm], bfr, acc2[fm][fn]);
    }
  }

  // ---- LN stats: per-row sum/sumsq; 16-lane shfl reduce + cross-wave LDS ----
  float bev[4];
  #pragma unroll
  for (int fn = 0; fn < 4; ++fn) bev[fn] = be[colb + fn * 16];
  #pragma unroll
  for (int fm = 0; fm < 4; ++fm) {
    #pragma unroll
    for (int r = 0; r < 4; ++r) {
      float s1 = 0.f, s2 = 0.f;
      #pragma unroll
      for (int fn = 0; fn < 4; ++fn) {
        float v = acc2[fm][fn][r] + bev[fn];
        s1 += v; s2 += v * v;
      }
      #pragma unroll
      for (int off = 1; off < 16; off <<= 1) {
        s1 += __shfl_xor(s1, off);
        s2 += __shfl_xor(s2, off);
      }
      if (c16 == 0) {
        const int m = h * 64 + fm * 16 + g * 4 + r;
        ps[m][cg] = s1; pq[m][cg] = s2;
      }
    }
  }
  __syncthreads();
  if (tid < 128) {
    float s = ps[tid][0] + ps[tid][1] + ps[tid][2] + ps[tid][3];
    float q = pq[tid][0] + pq[tid][1] + pq[tid][2] + pq[tid][3];
    float mu = s * 0.00390625f;
    float var = q * 0.00390625f - mu * mu;
    mus[tid] = mu;
    rss[tid] = rsqrtf(var + 1e-6f);
  }
  __syncthreads();

  // ---- store: (f - mu)*rs*g + b ----
  float gv[4], bhv[4];
  #pragma unroll
  for (int fn = 0; fn < 4; ++fn) {
    gv[fn] = lng[colb + fn * 16];
    bhv[fn] = lnb[colb + fn * 16];
  }
  #pragma unroll
  for (int fm = 0; fm < 4; ++fm) {
    #pragma unroll
    for (int r = 0; r < 4; ++r) {
      const int m = h * 64 + fm * 16 + g * 4 + r;
      const float mu = mus[m], rs = rss[m];
      float* orow = out + (size_t)(R0 + m) * 256;
      #pragma unroll
      for (int fn = 0; fn < 4; ++fn) {
        float v = acc2[fm][fn][r] + bev[fn];
        orow[colb + fn * 16] = (v - mu) * rs * gv[fn] + bhv[fn];
      }
    }
  }
#undef SCHED0
#undef RAW_BARRIER
#undef LOADA
#undef WRITEA
}

extern "C" void kernel_launch(void* const* d_in, const int* in_sizes, int n_in,
                              void* d_out, int out_size, void* d_ws, size_t ws_size,
                              hipStream_t stream) {
  const float* sub = (const float*)d_in[0];
  const float* obj = (const float*)d_in[1];
  const float* rel = (const float*)d_in[2];
  const float* W1 = (const float*)d_in[3];
  const float* b1 = (const float*)d_in[4];
  const float* W2 = (const float*)d_in[5];
  const float* b2 = (const float*)d_in[6];
  const float* W3 = (const float*)d_in[7];
  const float* b3 = (const float*)d_in[8];
  const float* We = (const float*)d_in[9];
  const float* be = (const float*)d_in[10];
  const float* lng = (const float*)d_in[11];
  const float* lnb = (const float*)d_in[12];
  float* out = (float*)d_out;

  float* ws = (float*)d_ws;
  float* l1p = ws;
  float* l2p = ws + 262144;
  unsigned short* W3g = (unsigned short*)(ws + 524288);
  unsigned short* Weg = W3g + 196608;

  prep_all<<<1280, 256, 0, stream>>>(sub, obj, W1, b1, W2, b2, W3, We, l1p, l2p, W3g, Weg);
  fused_main<<<1024, 512, 0, stream>>>(rel, l1p, l2p, W3g, Weg, b3, be, lng, lnb, out);
}